// Round 5
// baseline (99.709 us; speedup 1.0000x reference)
//
#include <hip/hip_runtime.h>

// BeamCTCDecoder — degenerate beam search == per-step argmax, then CTC collapse.
// logits: (N=128, C=128, T=2048) float32, layout n*C*T + c*T + t.
// out: (N, T) int32 — collapsed tokens, blank(0)-padded.
//
// Single fused kernel: argmax phase (4-way class split, 8 blocks/row), then the
// LAST block to finish a row (device-scope atomic counter) collapses that row
// inline. Counter array zeroed by a tiny hipMemsetAsync each launch.

constexpr int N = 128;
constexpr int C = 128;
constexpr int T = 2048;
constexpr int BPR = 8;                   // blocks per row

__global__ __launch_bounds__(256) void fused_kernel(const float* __restrict__ logits,
                                                    int* __restrict__ tokens,
                                                    int* __restrict__ cnt,
                                                    int* __restrict__ out) {
    // ---------------- Phase 1: argmax over classes, 4-way c-split ----------------
    // Block = 256 threads = 4 waves; wave g scans classes [g*32, g*32+32) for the
    // same 64 t-quads. 8 blocks/row -> 1024 blocks -> 16 waves/CU.
    __shared__ float sb[3][4][64];       // [group-1][component][tq] — stride-4B, conflict-free
    __shared__ int   si[3][4][64];
    __shared__ int   sdone;

    const int tid = threadIdx.x;
    const int tq  = tid & 63;            // t-quad slot (== lane)
    const int grp = tid >> 6;            // c-group 0..3 (== wave id)
    const int b   = blockIdx.x;
    const int n   = b >> 3;              // 8 blocks per row
    const int t4  = (b & 7) * 256 + tq * 4;

    const float* base = logits + (size_t)n * C * T + (size_t)(grp * 32) * T + t4;

    float4 best = make_float4(-__builtin_inff(), -__builtin_inff(),
                              -__builtin_inff(), -__builtin_inff());
    int4 bidx = make_int4(0, 0, 0, 0);

    #pragma unroll
    for (int cc = 0; cc < 32; cc += 8) {
        float4 v[8];
        #pragma unroll
        for (int j = 0; j < 8; ++j)
            v[j] = *(const float4*)(base + (size_t)(cc + j) * T);
        #pragma unroll
        for (int j = 0; j < 8; ++j) {
            const int c = cc + j;
            // strict > keeps the FIRST max (matches jnp.argmax tie-break)
            if (v[j].x > best.x) { best.x = v[j].x; bidx.x = c; }
            if (v[j].y > best.y) { best.y = v[j].y; bidx.y = c; }
            if (v[j].z > best.z) { best.z = v[j].z; bidx.z = c; }
            if (v[j].w > best.w) { best.w = v[j].w; bidx.w = c; }
        }
    }

    if (grp > 0) {                       // waves 1-3 publish (scalar, conflict-free)
        sb[grp - 1][0][tq] = best.x; si[grp - 1][0][tq] = bidx.x + grp * 32;
        sb[grp - 1][1][tq] = best.y; si[grp - 1][1][tq] = bidx.y + grp * 32;
        sb[grp - 1][2][tq] = best.z; si[grp - 1][2][tq] = bidx.z + grp * 32;
        sb[grp - 1][3][tq] = best.w; si[grp - 1][3][tq] = bidx.w + grp * 32;
    }
    __syncthreads();
    if (grp == 0) {                      // wave 0 combines + writes tokens
        #pragma unroll
        for (int g = 0; g < 3; ++g) {
            // higher groups win only on strict > -> ties keep lowest class
            float f;
            f = sb[g][0][tq]; if (f > best.x) { best.x = f; bidx.x = si[g][0][tq]; }
            f = sb[g][1][tq]; if (f > best.y) { best.y = f; bidx.y = si[g][1][tq]; }
            f = sb[g][2][tq]; if (f > best.z) { best.z = f; bidx.z = si[g][2][tq]; }
            f = sb[g][3][tq]; if (f > best.w) { best.w = f; bidx.w = si[g][3][tq]; }
        }
        *(int4*)(tokens + (size_t)n * T + t4) = bidx;
    }

    // ---------------- Row completion: last block collapses the row ----------------
    __syncthreads();                     // token stores drained (vmcnt(0) before barrier)
    if (tid == 0) {
        __threadfence();                 // release: this block's token writes device-visible
        const int old = atomicAdd(&cnt[n], 1);
        sdone = (old == BPR - 1);
    }
    __syncthreads();
    if (!sdone) return;
    __threadfence();                     // acquire: invalidate caches before remote reads

    // ---------------- Phase 2: CTC collapse of row n (256 threads) ----------------
    const int* trow = tokens + (size_t)n * T;
    int* orow = out + (size_t)n * T;
    constexpr int PER = T / 256;         // 8
    const int t0 = tid * PER;

    int tok[PER];
    *(int4*)&tok[0] = *(const int4*)(trow + t0);
    *(int4*)&tok[4] = *(const int4*)(trow + t0 + 4);
    int prev = (t0 == 0) ? -1 : trow[t0 - 1];

    int kpos[PER];
    int cntk = 0;
    #pragma unroll
    for (int i = 0; i < PER; ++i) {
        const bool k = (tok[i] != 0) && (tok[i] != prev);
        kpos[i] = k ? cntk : -1;
        cntk += k ? 1 : 0;
        prev = tok[i];
    }

    // wave-level (64-lane) inclusive scan of per-thread counts
    const int lane = tid & 63;
    const int wid  = tid >> 6;           // 0..3
    int incl = cntk;
    #pragma unroll
    for (int d = 1; d < 64; d <<= 1) {
        int v = __shfl_up(incl, d, 64);
        if (lane >= d) incl += v;
    }

    __shared__ int wsum[4];
    if (lane == 63) wsum[wid] = incl;

    // zero-fill the output row before the barrier; scatter after
    const int4 z = make_int4(0, 0, 0, 0);
    *(int4*)(orow + t0)     = z;
    *(int4*)(orow + t0 + 4) = z;

    __syncthreads();

    int wbase = 0;
    #pragma unroll
    for (int w = 0; w < 4; ++w)
        if (w < wid) wbase += wsum[w];
    const int base2 = wbase + (incl - cntk);  // exclusive prefix for this thread

    #pragma unroll
    for (int i = 0; i < PER; ++i) {
        if (kpos[i] >= 0) orow[base2 + kpos[i]] = tok[i];
    }
}

extern "C" void kernel_launch(void* const* d_in, const int* in_sizes, int n_in,
                              void* d_out, int out_size, void* d_ws, size_t ws_size,
                              hipStream_t stream) {
    const float* logits = (const float*)d_in[0];
    int* out = (int*)d_out;
    int* tokens = (int*)d_ws;                    // N*T int32 = 1 MiB
    int* cnt = (int*)((char*)d_ws + (size_t)N * T * sizeof(int));  // N int32

    hipMemsetAsync(cnt, 0, N * sizeof(int), stream);  // zero row counters (capturable)
    fused_kernel<<<N * BPR, 256, 0, stream>>>(logits, tokens, cnt, out);
}

// Round 6
// 29.262 us; speedup vs baseline: 3.4075x; 3.4075x over previous
//
#include <hip/hip_runtime.h>

// BeamCTCDecoder — degenerate beam search == per-step argmax, then CTC collapse.
// logits: (N=128, C=128, T=2048) float32, layout n*C*T + c*T + t.
// out: (N, T) int32 — collapsed tokens, blank(0)-padded.
//
// Two kernels (fusion breaks codegen: R3/R5 both dropped to 28 VGPRs and
// latency-bound 0.5 TB/s). Kernel A block mapping is XCD-aligned with kernel B:
// row n's 8 argmax blocks are b = n, n+128, ..., n+896 -> all on XCD n%8
// (128 % 8 == 0), same XCD as collapse block n -> token reads are local-L2 hits.

constexpr int N = 128;
constexpr int C = 128;
constexpr int T = 2048;

// ---------------- Kernel A: argmax over classes, 4-way c-split ----------------
// Block = 256 threads = 4 waves; wave g scans classes [g*32, g*32+32) for the
// same 64 t-quads (256 consecutive t's -> 1 KiB contiguous per wave load).
// 8 blocks/row -> 1024 blocks -> 4 blocks/CU, 16 waves/CU.
__global__ __launch_bounds__(256) void argmax_kernel(const float* __restrict__ logits,
                                                     int* __restrict__ tokens) {
    __shared__ float sb[3][4][64];   // [group-1][component][tq] — stride-4B, conflict-free
    __shared__ int   si[3][4][64];

    const int tid = threadIdx.x;
    const int tq  = tid & 63;            // t-quad slot (== lane)
    const int grp = tid >> 6;            // c-group 0..3 (== wave id)
    const int b   = blockIdx.x;
    const int n   = b & 127;             // row — XCD(b) = b%8 = n%8, matches collapse block n
    const int t4  = (b >> 7) * 256 + tq * 4;

    const float* base = logits + (size_t)n * C * T + (size_t)(grp * 32) * T + t4;

    float4 best = make_float4(-__builtin_inff(), -__builtin_inff(),
                              -__builtin_inff(), -__builtin_inff());
    int4 bidx = make_int4(0, 0, 0, 0);

    #pragma unroll
    for (int cc = 0; cc < 32; cc += 8) {
        float4 v[8];
        #pragma unroll
        for (int j = 0; j < 8; ++j)
            v[j] = *(const float4*)(base + (size_t)(cc + j) * T);
        #pragma unroll
        for (int j = 0; j < 8; ++j) {
            const int c = cc + j;
            // strict > keeps the FIRST max (matches jnp.argmax tie-break)
            if (v[j].x > best.x) { best.x = v[j].x; bidx.x = c; }
            if (v[j].y > best.y) { best.y = v[j].y; bidx.y = c; }
            if (v[j].z > best.z) { best.z = v[j].z; bidx.z = c; }
            if (v[j].w > best.w) { best.w = v[j].w; bidx.w = c; }
        }
    }

    if (grp > 0) {                       // waves 1-3 publish (scalar, conflict-free)
        sb[grp - 1][0][tq] = best.x; si[grp - 1][0][tq] = bidx.x + grp * 32;
        sb[grp - 1][1][tq] = best.y; si[grp - 1][1][tq] = bidx.y + grp * 32;
        sb[grp - 1][2][tq] = best.z; si[grp - 1][2][tq] = bidx.z + grp * 32;
        sb[grp - 1][3][tq] = best.w; si[grp - 1][3][tq] = bidx.w + grp * 32;
    }
    __syncthreads();
    if (grp == 0) {                      // wave 0 combines + writes
        #pragma unroll
        for (int g = 0; g < 3; ++g) {
            // higher groups win only on strict > -> ties keep lowest class
            float f;
            f = sb[g][0][tq]; if (f > best.x) { best.x = f; bidx.x = si[g][0][tq]; }
            f = sb[g][1][tq]; if (f > best.y) { best.y = f; bidx.y = si[g][1][tq]; }
            f = sb[g][2][tq]; if (f > best.z) { best.z = f; bidx.z = si[g][2][tq]; }
            f = sb[g][3][tq]; if (f > best.w) { best.w = f; bidx.w = si[g][3][tq]; }
        }
        *(int4*)(tokens + (size_t)n * T + t4) = bidx;
    }
}

// ---------------- Kernel B: per-row CTC collapse ----------------
// One block (256 threads) per row n; each thread owns 8 consecutive t's.
// Block n runs on XCD n%8 — same XCD that produced row n's tokens (local L2).
__global__ __launch_bounds__(256) void collapse_kernel(const int* __restrict__ tokens,
                                                       int* __restrict__ out) {
    const int n = blockIdx.x;
    const int* trow = tokens + (size_t)n * T;
    int* orow = out + (size_t)n * T;
    const int tid = threadIdx.x;            // 0..255
    constexpr int PER = T / 256;            // 8
    const int t0 = tid * PER;

    int tok[PER];
    *(int4*)&tok[0] = *(const int4*)(trow + t0);
    *(int4*)&tok[4] = *(const int4*)(trow + t0 + 4);
    int prev = (t0 == 0) ? -1 : trow[t0 - 1];

    int kpos[PER];
    int cnt = 0;
    #pragma unroll
    for (int i = 0; i < PER; ++i) {
        const bool k = (tok[i] != 0) && (tok[i] != prev);
        kpos[i] = k ? cnt : -1;
        cnt += k ? 1 : 0;
        prev = tok[i];
    }

    // wave-level (64-lane) inclusive scan of per-thread counts
    const int lane = tid & 63;
    const int wid  = tid >> 6;              // 0..3
    int incl = cnt;
    #pragma unroll
    for (int d = 1; d < 64; d <<= 1) {
        int v = __shfl_up(incl, d, 64);
        if (lane >= d) incl += v;
    }

    __shared__ int wsum[4];
    if (lane == 63) wsum[wid] = incl;

    // zero-fill the output row before the barrier; scatter after
    const int4 z = make_int4(0, 0, 0, 0);
    *(int4*)(orow + t0)     = z;
    *(int4*)(orow + t0 + 4) = z;

    __syncthreads();

    int wbase = 0;
    #pragma unroll
    for (int w = 0; w < 4; ++w)
        if (w < wid) wbase += wsum[w];
    const int base2 = wbase + (incl - cnt); // exclusive prefix for this thread

    #pragma unroll
    for (int i = 0; i < PER; ++i) {
        if (kpos[i] >= 0) orow[base2 + kpos[i]] = tok[i];
    }
}

extern "C" void kernel_launch(void* const* d_in, const int* in_sizes, int n_in,
                              void* d_out, int out_size, void* d_ws, size_t ws_size,
                              hipStream_t stream) {
    const float* logits = (const float*)d_in[0];
    int* out = (int*)d_out;
    int* tokens = (int*)d_ws;               // N*T int32 = 1 MiB scratch

    argmax_kernel<<<N * 8, 256, 0, stream>>>(logits, tokens);
    collapse_kernel<<<N, 256, 0, stream>>>(tokens, out);
}

// Round 7
// 27.633 us; speedup vs baseline: 3.6083x; 1.0589x over previous
//
#include <hip/hip_runtime.h>

// BeamCTCDecoder — degenerate beam search == per-step argmax, then CTC collapse.
// logits: (N=128, C=128, T=2048) float32, layout n*C*T + c*T + t.
// out: (N, T) int32 — collapsed tokens, blank(0)-padded.
//
// Two kernels (fusion breaks codegen: R3/R5 dropped to 28 VGPRs, 0.5 TB/s).
// A: argmax, 4-way class split, symmetric all-wave epilogue, zero-fills out.
// B: scatter-only CTC collapse (zeros already in place from A).

constexpr int N = 128;
constexpr int C = 128;
constexpr int T = 2048;

// ---------------- Kernel A: argmax over classes, 4-way c-split ----------------
// Block = 256 threads = 4 waves; wave g scans classes [g*32, g*32+32) for the
// same 64 t-quads (256 consecutive t's -> 1 KiB contiguous per wave load).
// 8 blocks/row (n = b>>3, R2/R4 mapping), 1024 blocks, 16 waves/CU.
__global__ __launch_bounds__(256) void argmax_kernel(const float* __restrict__ logits,
                                                     int* __restrict__ tokens,
                                                     int* __restrict__ out) {
    __shared__ float sb[4][64][4];   // [group][tq][comp] — combine read = bank tid%32, conflict-free
    __shared__ int   si[4][64][4];

    const int tid   = threadIdx.x;
    const int tq    = tid & 63;          // t-quad slot (== lane)
    const int grp   = tid >> 6;          // c-group 0..3 (== wave id)
    const int b     = blockIdx.x;
    const int n     = b >> 3;            // 8 blocks per row
    const int chunk = b & 7;
    const int t4    = chunk * 256 + tq * 4;

    const float* base = logits + (size_t)n * C * T + (size_t)(grp * 32) * T + t4;

    float4 best = make_float4(-__builtin_inff(), -__builtin_inff(),
                              -__builtin_inff(), -__builtin_inff());
    int4 bidx = make_int4(0, 0, 0, 0);

    #pragma unroll
    for (int cc = 0; cc < 32; cc += 8) {
        float4 v[8];
        #pragma unroll
        for (int j = 0; j < 8; ++j)
            v[j] = *(const float4*)(base + (size_t)(cc + j) * T);
        #pragma unroll
        for (int j = 0; j < 8; ++j) {
            const int c = cc + j;
            // strict > keeps the FIRST max (matches jnp.argmax tie-break)
            if (v[j].x > best.x) { best.x = v[j].x; bidx.x = c; }
            if (v[j].y > best.y) { best.y = v[j].y; bidx.y = c; }
            if (v[j].z > best.z) { best.z = v[j].z; bidx.z = c; }
            if (v[j].w > best.w) { best.w = v[j].w; bidx.w = c; }
        }
    }

    // all 4 waves publish (float4/int4 stores, 2 lanes/bank = free)
    *(float4*)sb[grp][tq] = best;
    int4 gi = make_int4(bidx.x + grp * 32, bidx.y + grp * 32,
                        bidx.z + grp * 32, bidx.w + grp * 32);
    *(int4*)si[grp][tq] = gi;

    // zero-fill this block's out chunk (independent of LDS; overlaps barrier)
    out[(size_t)n * T + chunk * 256 + tid] = 0;

    __syncthreads();

    // symmetric combine: each thread owns one (t-quad, component)
    const int comp = tid & 3;
    const int q    = tid >> 2;
    float fb = sb[0][q][comp];
    int   ib = si[0][q][comp];
    #pragma unroll
    for (int g = 1; g < 4; ++g) {
        // higher groups win only on strict > -> ties keep lowest class
        const float f = sb[g][q][comp];
        if (f > fb) { fb = f; ib = si[g][q][comp]; }
    }
    // scalar store, tid-contiguous -> coalesced 1 KiB per block
    tokens[(size_t)n * T + chunk * 256 + tid] = ib;
}

// ---------------- Kernel B: per-row CTC collapse (scatter-only) ----------------
// One block (256 threads) per row n; each thread owns 8 consecutive t's.
// out row already zero-filled by kernel A.
__global__ __launch_bounds__(256) void collapse_kernel(const int* __restrict__ tokens,
                                                       int* __restrict__ out) {
    const int n = blockIdx.x;
    const int* trow = tokens + (size_t)n * T;
    int* orow = out + (size_t)n * T;
    const int tid = threadIdx.x;            // 0..255
    constexpr int PER = T / 256;            // 8
    const int t0 = tid * PER;

    int tok[PER];
    *(int4*)&tok[0] = *(const int4*)(trow + t0);
    *(int4*)&tok[4] = *(const int4*)(trow + t0 + 4);
    int prev = (t0 == 0) ? -1 : trow[t0 - 1];

    int kpos[PER];
    int cnt = 0;
    #pragma unroll
    for (int i = 0; i < PER; ++i) {
        const bool k = (tok[i] != 0) && (tok[i] != prev);
        kpos[i] = k ? cnt : -1;
        cnt += k ? 1 : 0;
        prev = tok[i];
    }

    // wave-level (64-lane) inclusive scan of per-thread counts
    const int lane = tid & 63;
    const int wid  = tid >> 6;              // 0..3
    int incl = cnt;
    #pragma unroll
    for (int d = 1; d < 64; d <<= 1) {
        int v = __shfl_up(incl, d, 64);
        if (lane >= d) incl += v;
    }

    __shared__ int wsum[4];
    if (lane == 63) wsum[wid] = incl;
    __syncthreads();

    int wbase = 0;
    #pragma unroll
    for (int w = 0; w < 4; ++w)
        if (w < wid) wbase += wsum[w];
    const int base2 = wbase + (incl - cnt); // exclusive prefix for this thread

    #pragma unroll
    for (int i = 0; i < PER; ++i) {
        if (kpos[i] >= 0) orow[base2 + kpos[i]] = tok[i];
    }
}

extern "C" void kernel_launch(void* const* d_in, const int* in_sizes, int n_in,
                              void* d_out, int out_size, void* d_ws, size_t ws_size,
                              hipStream_t stream) {
    const float* logits = (const float*)d_in[0];
    int* out = (int*)d_out;
    int* tokens = (int*)d_ws;               // N*T int32 = 1 MiB scratch

    argmax_kernel<<<N * 8, 256, 0, stream>>>(logits, tokens, out);
    collapse_kernel<<<N, 256, 0, stream>>>(tokens, out);
}

// Round 9
// 27.091 us; speedup vs baseline: 3.6806x; 1.0200x over previous
//
#include <hip/hip_runtime.h>

// BeamCTCDecoder — degenerate beam search == per-step argmax, then CTC collapse.
// logits: (N=128, C=128, T=2048) float32, layout n*C*T + c*T + t.
// out: (N, T) int32 — collapsed tokens, blank(0)-padded.
//
// Two kernels (fusion breaks codegen: R3/R5 dropped to 28 VGPRs, 0.5 TB/s).
// A: argmax, 4-way class split, NON-TEMPORAL logits loads (read-once stream),
//    symmetric all-wave epilogue, zero-fills out.
// B: scatter-only CTC collapse (zeros already in place from A).

constexpr int N = 128;
constexpr int C = 128;
constexpr int T = 2048;

typedef float f32x4 __attribute__((ext_vector_type(4)));  // native vec for NT builtin

// ---------------- Kernel A: argmax over classes, 4-way c-split ----------------
__global__ __launch_bounds__(256) void argmax_kernel(const float* __restrict__ logits,
                                                     int* __restrict__ tokens,
                                                     int* __restrict__ out) {
    __shared__ float sb[4][64][4];   // [group][tq][comp] — combine read bank = tid%32, conflict-free
    __shared__ int   si[4][64][4];

    const int tid   = threadIdx.x;
    const int tq    = tid & 63;          // t-quad slot (== lane)
    const int grp   = tid >> 6;          // c-group 0..3 (== wave id)
    const int b     = blockIdx.x;
    const int n     = b >> 3;            // 8 blocks per row
    const int chunk = b & 7;
    const int t4    = chunk * 256 + tq * 4;

    const float* base = logits + (size_t)n * C * T + (size_t)(grp * 32) * T + t4;

    float bx = -__builtin_inff(), by = bx, bz = bx, bw = bx;
    int ix = 0, iy = 0, iz = 0, iw = 0;

    #pragma unroll
    for (int cc = 0; cc < 32; cc += 8) {
        f32x4 v[8];
        #pragma unroll
        for (int j = 0; j < 8; ++j)
            v[j] = __builtin_nontemporal_load((const f32x4*)(base + (size_t)(cc + j) * T));
        #pragma unroll
        for (int j = 0; j < 8; ++j) {
            const int c = cc + j;
            // strict > keeps the FIRST max (matches jnp.argmax tie-break)
            if (v[j].x > bx) { bx = v[j].x; ix = c; }
            if (v[j].y > by) { by = v[j].y; iy = c; }
            if (v[j].z > bz) { bz = v[j].z; iz = c; }
            if (v[j].w > bw) { bw = v[j].w; iw = c; }
        }
    }

    // all 4 waves publish (16B stores, 2 lanes/bank = free)
    sb[grp][tq][0] = bx; sb[grp][tq][1] = by; sb[grp][tq][2] = bz; sb[grp][tq][3] = bw;
    si[grp][tq][0] = ix + grp * 32; si[grp][tq][1] = iy + grp * 32;
    si[grp][tq][2] = iz + grp * 32; si[grp][tq][3] = iw + grp * 32;

    // zero-fill this block's out chunk (independent of LDS; overlaps barrier)
    out[(size_t)n * T + chunk * 256 + tid] = 0;

    __syncthreads();

    // symmetric combine: each thread owns one (t-quad, component)
    const int comp = tid & 3;
    const int q    = tid >> 2;
    float fb = sb[0][q][comp];
    int   ib = si[0][q][comp];
    #pragma unroll
    for (int g = 1; g < 4; ++g) {
        // higher groups win only on strict > -> ties keep lowest class
        const float f = sb[g][q][comp];
        if (f > fb) { fb = f; ib = si[g][q][comp]; }
    }
    // scalar store, tid-contiguous -> coalesced 1 KiB per block (normal store:
    // tokens are re-read by kernel B right away, keep them L2-resident)
    tokens[(size_t)n * T + chunk * 256 + tid] = ib;
}

// ---------------- Kernel B: per-row CTC collapse (scatter-only) ----------------
__global__ __launch_bounds__(256) void collapse_kernel(const int* __restrict__ tokens,
                                                       int* __restrict__ out) {
    const int n = blockIdx.x;
    const int* trow = tokens + (size_t)n * T;
    int* orow = out + (size_t)n * T;
    const int tid = threadIdx.x;            // 0..255
    constexpr int PER = T / 256;            // 8
    const int t0 = tid * PER;

    int tok[PER];
    *(int4*)&tok[0] = *(const int4*)(trow + t0);
    *(int4*)&tok[4] = *(const int4*)(trow + t0 + 4);
    int prev = (t0 == 0) ? -1 : trow[t0 - 1];

    int kpos[PER];
    int cnt = 0;
    #pragma unroll
    for (int i = 0; i < PER; ++i) {
        const bool k = (tok[i] != 0) && (tok[i] != prev);
        kpos[i] = k ? cnt : -1;
        cnt += k ? 1 : 0;
        prev = tok[i];
    }

    // wave-level (64-lane) inclusive scan of per-thread counts
    const int lane = tid & 63;
    const int wid  = tid >> 6;              // 0..3
    int incl = cnt;
    #pragma unroll
    for (int d = 1; d < 64; d <<= 1) {
        int v = __shfl_up(incl, d, 64);
        if (lane >= d) incl += v;
    }

    __shared__ int wsum[4];
    if (lane == 63) wsum[wid] = incl;
    __syncthreads();

    int wbase = 0;
    #pragma unroll
    for (int w = 0; w < 4; ++w)
        if (w < wid) wbase += wsum[w];
    const int base2 = wbase + (incl - cnt); // exclusive prefix for this thread

    #pragma unroll
    for (int i = 0; i < PER; ++i) {
        if (kpos[i] >= 0) orow[base2 + kpos[i]] = tok[i];
    }
}

extern "C" void kernel_launch(void* const* d_in, const int* in_sizes, int n_in,
                              void* d_out, int out_size, void* d_ws, size_t ws_size,
                              hipStream_t stream) {
    const float* logits = (const float*)d_in[0];
    int* out = (int*)d_out;
    int* tokens = (int*)d_ws;               // N*T int32 = 1 MiB scratch

    argmax_kernel<<<N * 8, 256, 0, stream>>>(logits, tokens, out);
    collapse_kernel<<<N, 256, 0, stream>>>(tokens, out);
}